// Round 1
// baseline (1375.275 us; speedup 1.0000x reference)
//
#include <hip/hip_runtime.h>
#include <stdint.h>

#define T_SEQ 2048
#define DMODEL 2048
#define NH 16
#define NKV 8
#define DHEAD 128
#define DFF 8192

typedef float f32x4 __attribute__((ext_vector_type(4)));
typedef float f32x2 __attribute__((ext_vector_type(2)));
typedef __bf16 bf16x8 __attribute__((ext_vector_type(8)));
typedef unsigned short ushort_t;

typedef __attribute__((address_space(1))) void gvoid;
typedef __attribute__((address_space(3))) void lvoid;

__device__ inline unsigned short f2bf(float f) {
  unsigned int u = __float_as_uint(f);
  u += 0x7fffu + ((u >> 16) & 1u);
  return (unsigned short)(u >> 16);
}
__device__ inline float bf2f(unsigned short h) {
  return __uint_as_float(((unsigned int)h) << 16);
}

__device__ inline void gload_lds16(const void* g, void* l) {
  // 16B per lane; LDS dest is wave-uniform base + lane*16 (HW rule)
  __builtin_amdgcn_global_load_lds((gvoid*)g, (lvoid*)l, 16, 0, 0);
}

// ---------------------------------------------------------------------------
// Transpose + convert: in f32/bf16 [R][C] -> out bf16 [C][R].  Tile 64x64.
// LDS col-chunk XOR swizzle to keep phase-2 reads from 16-way conflicting.
// ---------------------------------------------------------------------------
template <typename TIN>
__global__ __launch_bounds__(256) void k_transpose_bf16(const TIN* __restrict__ in,
                                                        ushort_t* __restrict__ out,
                                                        int R, int C) {
  __shared__ float tile[64 * 72];
  int tid = threadIdx.x;
  int r0 = blockIdx.y * 64, c0 = blockIdx.x * 64;
  int rl = tid >> 4;   // 0..15
  int cc = tid & 15;   // 16B col chunk
#pragma unroll
  for (int i = 0; i < 4; ++i) {
    int row = rl + i * 16;
    const TIN* src = in + (size_t)(r0 + row) * C + c0 + cc * 4;
    float v0, v1, v2, v3;
    if constexpr (sizeof(TIN) == 4) {
      f32x4 v = *(const f32x4*)src;
      v0 = v.x; v1 = v.y; v2 = v.z; v3 = v.w;
    } else {
      ushort4 v = *(const ushort4*)src;
      v0 = bf2f(v.x); v1 = bf2f(v.y); v2 = bf2f(v.z); v3 = bf2f(v.w);
    }
    int chunk = cc ^ (row & 15);
    f32x4 t = {v0, v1, v2, v3};
    *(f32x4*)&tile[row * 72 + chunk * 4] = t;
  }
  __syncthreads();
#pragma unroll
  for (int i = 0; i < 4; ++i) {
    int nrow = rl + i * 16;   // output row local = input col
    int k4 = cc * 4;          // output col local base = input row
    ushort4 o;
    {
      int k = k4 + 0;
      o.x = f2bf(tile[k * 72 + (((nrow >> 2) ^ (k & 15)) << 2) + (nrow & 3)]);
      k = k4 + 1;
      o.y = f2bf(tile[k * 72 + (((nrow >> 2) ^ (k & 15)) << 2) + (nrow & 3)]);
      k = k4 + 2;
      o.z = f2bf(tile[k * 72 + (((nrow >> 2) ^ (k & 15)) << 2) + (nrow & 3)]);
      k = k4 + 3;
      o.w = f2bf(tile[k * 72 + (((nrow >> 2) ^ (k & 15)) << 2) + (nrow & 3)]);
    }
    *(ushort4*)(out + (size_t)(c0 + nrow) * R + r0 + k4) = o;
  }
}

// ---------------------------------------------------------------------------
// RMSNorm over D=2048, one block (256 thr) per row.  BF16OUT -> ushort bf16.
// ---------------------------------------------------------------------------
template <int BF16OUT>
__global__ __launch_bounds__(256) void k_rmsnorm(const float* __restrict__ X,
                                                 const float* __restrict__ W,
                                                 void* __restrict__ OUT) {
  int row = blockIdx.x, tid = threadIdx.x;
  const float* xr = X + (size_t)row * DMODEL;
  f32x4 x0 = *(const f32x4*)(xr + tid * 4);
  f32x4 x1 = *(const f32x4*)(xr + 1024 + tid * 4);
  float ss = x0.x * x0.x + x0.y * x0.y + x0.z * x0.z + x0.w * x0.w +
             x1.x * x1.x + x1.y * x1.y + x1.z * x1.z + x1.w * x1.w;
#pragma unroll
  for (int o = 1; o < 64; o <<= 1) ss += __shfl_xor(ss, o, 64);
  __shared__ float red[4];
  int w = tid >> 6;
  if ((tid & 63) == 0) red[w] = ss;
  __syncthreads();
  float tot = red[0] + red[1] + red[2] + red[3];
  float sc = rsqrtf(tot / (float)DMODEL + 1e-6f);
  f32x4 w0 = *(const f32x4*)(W + tid * 4);
  f32x4 w1 = *(const f32x4*)(W + 1024 + tid * 4);
  if constexpr (BF16OUT) {
    ushort_t* o = (ushort_t*)OUT + (size_t)row * DMODEL;
    ushort4 a, b;
    a.x = f2bf(x0.x * sc * w0.x); a.y = f2bf(x0.y * sc * w0.y);
    a.z = f2bf(x0.z * sc * w0.z); a.w = f2bf(x0.w * sc * w0.w);
    b.x = f2bf(x1.x * sc * w1.x); b.y = f2bf(x1.y * sc * w1.y);
    b.z = f2bf(x1.z * sc * w1.z); b.w = f2bf(x1.w * sc * w1.w);
    *(ushort4*)(o + tid * 4) = a;
    *(ushort4*)(o + 1024 + tid * 4) = b;
  } else {
    float* o = (float*)OUT + (size_t)row * DMODEL;
    f32x4 a = {x0.x * sc * w0.x, x0.y * sc * w0.y, x0.z * sc * w0.z, x0.w * sc * w0.w};
    f32x4 b = {x1.x * sc * w1.x, x1.y * sc * w1.y, x1.z * sc * w1.z, x1.w * sc * w1.w};
    *(f32x4*)(o + tid * 4) = a;
    *(f32x4*)(o + 1024 + tid * 4) = b;
  }
}

// ---------------------------------------------------------------------------
// GEMM  C[M,N] = A[M,K](bf16) * B(from BT bf16 [N][K]).  128x128 tile, BK=32,
// 4 waves (2x2 of 64x64), mfma_f32_16x16x32_bf16, global_load_lds staging.
// EPI: 0 store f32, 1 store f32 + residual, 2 silu(GIN)*acc -> bf16.
// ---------------------------------------------------------------------------
#define EPI_STORE 0
#define EPI_ADDRES 1
#define EPI_SILU 2

template <int EPI>
__global__ __launch_bounds__(256) void k_gemm(const ushort_t* __restrict__ A,
                                              const ushort_t* __restrict__ BT,
                                              const float* __restrict__ RES,
                                              const float* __restrict__ GIN,
                                              float* __restrict__ CF,
                                              ushort_t* __restrict__ CB,
                                              int M, int N, int K) {
  __shared__ ushort_t As[128 * 32];
  __shared__ ushort_t Bs[128 * 32];
  int tid = threadIdx.x;
  int w = tid >> 6, l = tid & 63;
  int wm = w >> 1, wn = w & 1;
  int m0 = blockIdx.y * 128, n0 = blockIdx.x * 128;
  int lr = l & 15, lg = l >> 4;
  f32x4 acc[4][4] = {};
  for (int kt = 0; kt < K; kt += 32) {
#pragma unroll
    for (int it = 0; it < 2; ++it) {
      int idx = it * 256 + tid;
      int r = idx >> 2, c = idx & 3;
      gload_lds16(A + (size_t)(m0 + r) * K + kt + c * 8, &As[(it * 256 + w * 64) * 8]);
      gload_lds16(BT + (size_t)(n0 + r) * K + kt + c * 8, &Bs[(it * 256 + w * 64) * 8]);
    }
    __syncthreads();
    const bf16x8* Av = (const bf16x8*)As;
    const bf16x8* Bv = (const bf16x8*)Bs;
    bf16x8 af[4], bfr[4];
#pragma unroll
    for (int i = 0; i < 4; ++i) {
      af[i] = Av[(wm * 64 + i * 16 + lr) * 4 + lg];
      bfr[i] = Bv[(wn * 64 + i * 16 + lr) * 4 + lg];
    }
#pragma unroll
    for (int i = 0; i < 4; ++i)
#pragma unroll
      for (int j = 0; j < 4; ++j)
        acc[i][j] = __builtin_amdgcn_mfma_f32_16x16x32_bf16(af[i], bfr[j], acc[i][j], 0, 0, 0);
    __syncthreads();
  }
#pragma unroll
  for (int i = 0; i < 4; ++i)
#pragma unroll
    for (int j = 0; j < 4; ++j)
#pragma unroll
      for (int r = 0; r < 4; ++r) {
        int m = m0 + wm * 64 + i * 16 + lg * 4 + r;
        int n = n0 + wn * 64 + j * 16 + lr;
        size_t off = (size_t)m * N + n;
        float v = acc[i][j][r];
        if constexpr (EPI == EPI_STORE) {
          CF[off] = v;
        } else if constexpr (EPI == EPI_ADDRES) {
          CF[off] = v + RES[off];
        } else {
          float gv = GIN[off];
          float s = gv / (1.f + __expf(-gv));
          CB[off] = f2bf(s * v);
        }
      }
}

// ---------------------------------------------------------------------------
// Post-QKV: per-head RMSNorm (q,k) + RoPE + bf16 cast.  Block=256 per token,
// wave handles 8 of 32 head-slots (0-15 q, 16-23 k, 24-31 v), 2 dims/lane.
// ---------------------------------------------------------------------------
__global__ __launch_bounds__(256) void k_qkv_post(const float* __restrict__ QKV,
                                                  const float* __restrict__ QNW,
                                                  const float* __restrict__ KNW,
                                                  const int* __restrict__ POS,
                                                  ushort_t* __restrict__ Qb,
                                                  ushort_t* __restrict__ Kb,
                                                  ushort_t* __restrict__ Vb) {
  int t = blockIdx.x;
  int tid = threadIdx.x;
  int w = tid >> 6, l = tid & 63;
  float pos = (float)POS[t];
  const float* base = QKV + (size_t)t * 4096;
  int i0 = 2 * (l & 31);
  const float K2 = 19.931568569324174f / 64.f;  // log2(1e6)/64
  float ang0 = pos * exp2f(-(float)i0 * K2);
  float ang1 = pos * exp2f(-(float)(i0 + 1) * K2);
  float cs0 = cosf(ang0), sn0 = sinf(ang0);
  float cs1 = cosf(ang1), sn1 = sinf(ang1);
#pragma unroll
  for (int si = 0; si < 8; ++si) {
    int slot = w + si * 4;
    const float* p = base + slot * 128;
    f32x2 xv = *(const f32x2*)(p + l * 2);
    float v0 = xv.x, v1 = xv.y;
    float ss = v0 * v0 + v1 * v1;
#pragma unroll
    for (int o = 1; o < 64; o <<= 1) ss += __shfl_xor(ss, o, 64);
    if (slot < 24) {
      float sc = rsqrtf(ss / 128.f + 1e-6f);
      const float* wn = (slot < 16) ? QNW : KNW;
      f32x2 wv = *(const f32x2*)(wn + l * 2);
      v0 = v0 * sc * wv.x;
      v1 = v1 * sc * wv.y;
      // rotate_half: partner lane l^32 holds d +/- 64
      float p0 = __shfl_xor(v0, 32, 64);
      float p1 = __shfl_xor(v1, 32, 64);
      float r0 = (l < 32) ? -p0 : p0;
      float r1 = (l < 32) ? -p1 : p1;
      v0 = v0 * cs0 + r0 * sn0;
      v1 = v1 * cs1 + r1 * sn1;
    }
    ushort2 uv;
    uv.x = f2bf(v0);
    uv.y = f2bf(v1);
    ushort_t* dst;
    if (slot < 16)
      dst = Qb + (size_t)t * 2048 + slot * 128 + l * 2;
    else if (slot < 24)
      dst = Kb + (size_t)t * 1024 + (slot - 16) * 128 + l * 2;
    else
      dst = Vb + (size_t)t * 1024 + (slot - 24) * 128 + l * 2;
    *(ushort2*)dst = uv;
  }
}

// ---------------------------------------------------------------------------
// Flash attention, ragged causal (segment) mask.  1 wave per (16 q rows, head).
// 32-key tiles; QK^T and PV both 16x16x32 MFMA; V pre-transposed [HK*128][T].
// ---------------------------------------------------------------------------
__global__ __launch_bounds__(64) void k_flash(const ushort_t* __restrict__ Qb,
                                              const ushort_t* __restrict__ Kb,
                                              const ushort_t* __restrict__ VT,
                                              const int* __restrict__ SEG,
                                              ushort_t* __restrict__ Ob) {
  __shared__ ushort_t Pl[16 * 40];
  int l = threadIdx.x;
  int qt = blockIdx.x, h = blockIdx.y;
  int q0 = qt * 16;
  int lr = l & 15, lg = l >> 4;
  int kvh = h >> 1;
  bf16x8 qf[4];
  {
    const bf16x8* qv = (const bf16x8*)(Qb + (size_t)(q0 + lr) * 2048 + h * 128);
#pragma unroll
    for (int kk = 0; kk < 4; ++kk) qf[kk] = qv[kk * 4 + lg];
  }
  int segq[4];
#pragma unroll
  for (int r = 0; r < 4; ++r) segq[r] = SEG[q0 + lg * 4 + r];
  int target = SEG[q0];
  int lo = 0, hi = q0;
  while (lo < hi) {
    int mid = (lo + hi) >> 1;
    if (SEG[mid] < target) lo = mid + 1; else hi = mid;
  }
  int s_start = lo & ~31;
  float m_run[4], l_run[4];
  f32x4 acc[8] = {};
#pragma unroll
  for (int r = 0; r < 4; ++r) { m_run[r] = -1e30f; l_run[r] = 0.f; }
  const float scale = 0.08838834764831845f;  // 1/sqrt(128)
  for (int s0 = s_start; s0 < q0 + 16; s0 += 32) {
    int sa = s0 + lr, sb = s0 + 16 + lr;
    int sac = min(sa, T_SEQ - 1), sbc = min(sb, T_SEQ - 1);
    f32x4 SA = {}, SB = {};
    const bf16x8* ka = (const bf16x8*)(Kb + (size_t)sac * 1024 + kvh * 128);
    const bf16x8* kb = (const bf16x8*)(Kb + (size_t)sbc * 1024 + kvh * 128);
#pragma unroll
    for (int kk = 0; kk < 4; ++kk) {
      SA = __builtin_amdgcn_mfma_f32_16x16x32_bf16(qf[kk], ka[kk * 4 + lg], SA, 0, 0, 0);
      SB = __builtin_amdgcn_mfma_f32_16x16x32_bf16(qf[kk], kb[kk * 4 + lg], SB, 0, 0, 0);
    }
    int sga = SEG[sac], sgb = SEG[sbc];
    float al[4], pA[4], pB[4];
#pragma unroll
    for (int r = 0; r < 4; ++r) {
      int qrow = q0 + lg * 4 + r;
      float xa = (sa <= qrow && sga == segq[r]) ? SA[r] * scale : -1e30f;
      float xb = (sb <= qrow && sgb == segq[r]) ? SB[r] * scale : -1e30f;
      float mx = fmaxf(xa, xb);
#pragma unroll
      for (int o = 1; o < 16; o <<= 1) mx = fmaxf(mx, __shfl_xor(mx, o, 64));
      float nm = fmaxf(m_run[r], mx);
      float ea = __expf(xa - nm), eb = __expf(xb - nm);
      float rs = ea + eb;
#pragma unroll
      for (int o = 1; o < 16; o <<= 1) rs += __shfl_xor(rs, o, 64);
      al[r] = __expf(m_run[r] - nm);
      l_run[r] = l_run[r] * al[r] + rs;
      m_run[r] = nm;
      pA[r] = ea;
      pB[r] = eb;
    }
#pragma unroll
    for (int c = 0; c < 8; ++c)
#pragma unroll
      for (int r = 0; r < 4; ++r) acc[c][r] *= al[r];
    __syncthreads();
#pragma unroll
    for (int r = 0; r < 4; ++r) {
      Pl[(lg * 4 + r) * 40 + lr] = f2bf(pA[r]);
      Pl[(lg * 4 + r) * 40 + 16 + lr] = f2bf(pB[r]);
    }
    __syncthreads();
    bf16x8 pa = *(const bf16x8*)&Pl[lr * 40 + lg * 8];
    int sbase = min(s0 + lg * 8, T_SEQ - 8);
#pragma unroll
    for (int c = 0; c < 8; ++c) {
      bf16x8 vb = *(const bf16x8*)(VT + (size_t)(kvh * 128 + c * 16 + lr) * T_SEQ + sbase);
      acc[c] = __builtin_amdgcn_mfma_f32_16x16x32_bf16(pa, vb, acc[c], 0, 0, 0);
    }
  }
#pragma unroll
  for (int c = 0; c < 8; ++c)
#pragma unroll
    for (int r = 0; r < 4; ++r) {
      float ov = acc[c][r] / l_run[r];
      Ob[(size_t)(q0 + lg * 4 + r) * 2048 + h * 128 + c * 16 + lr] = f2bf(ov);
    }
}

// ---------------------------------------------------------------------------
extern "C" void kernel_launch(void* const* d_in, const int* in_sizes, int n_in,
                              void* d_out, int out_size, void* d_ws, size_t ws_size,
                              hipStream_t stream) {
  const float* hidden = (const float*)d_in[0];
  const float* ln1 = (const float*)d_in[1];
  const float* ln2 = (const float*)d_in[2];
  const float* wq = (const float*)d_in[3];
  const float* wk = (const float*)d_in[4];
  const float* wv = (const float*)d_in[5];
  const float* wo = (const float*)d_in[6];
  const float* qnw = (const float*)d_in[7];
  const float* knw = (const float*)d_in[8];
  const float* wg = (const float*)d_in[9];
  const float* wu = (const float*)d_in[10];
  const float* wd = (const float*)d_in[11];
  const float* fnw = (const float*)d_in[12];
  const int* seg = (const int*)d_in[13];
  const int* pos = (const int*)d_in[14];
  float* out = (float*)d_out;

  char* ws = (char*)d_ws;
  size_t off = 0;
  auto alloc = [&](size_t bytes) {
    char* p = ws + off;
    off += (bytes + 255) & ~(size_t)255;
    return p;
  };
  ushort_t* wT = (ushort_t*)alloc((size_t)DFF * DMODEL * 2);       // 33.5MB rotating
  ushort_t* hbuf = (ushort_t*)alloc((size_t)T_SEQ * DMODEL * 2);   // norm out bf16
  float* qkv = (float*)alloc((size_t)T_SEQ * 4096 * 4);
  ushort_t* qb = (ushort_t*)alloc((size_t)T_SEQ * 2048 * 2);
  ushort_t* kb = (ushort_t*)alloc((size_t)T_SEQ * 1024 * 2);
  ushort_t* vb = (ushort_t*)alloc((size_t)T_SEQ * 1024 * 2);
  ushort_t* vT = (ushort_t*)alloc((size_t)T_SEQ * 1024 * 2);
  ushort_t* ob = (ushort_t*)alloc((size_t)T_SEQ * 2048 * 2);
  float* gbuf = (float*)alloc((size_t)T_SEQ * DFF * 4);
  ushort_t* mbuf = (ushort_t*)alloc((size_t)T_SEQ * DFF * 2);
  (void)ws_size; (void)in_sizes; (void)n_in; (void)out_size;  // total ~196MB

  dim3 b256(256), b64(64);
  for (int lyr = 0; lyr < 2; ++lyr) {
    const float* xsrc = (lyr == 0) ? hidden : out;
    k_rmsnorm<1><<<T_SEQ, b256, 0, stream>>>(xsrc, ln1 + (size_t)lyr * DMODEL, hbuf);

    const float* wql = wq + (size_t)lyr * DMODEL * 2048;
    const float* wkl = wk + (size_t)lyr * DMODEL * 1024;
    const float* wvl = wv + (size_t)lyr * DMODEL * 1024;
    k_transpose_bf16<float><<<dim3(32, 32), b256, 0, stream>>>(wql, wT, 2048, 2048);
    k_transpose_bf16<float><<<dim3(16, 32), b256, 0, stream>>>(wkl, wT + (size_t)2048 * 2048, 2048, 1024);
    k_transpose_bf16<float><<<dim3(16, 32), b256, 0, stream>>>(wvl, wT + (size_t)3072 * 2048, 2048, 1024);
    k_gemm<EPI_STORE><<<dim3(32, 16), b256, 0, stream>>>(hbuf, wT, nullptr, nullptr, qkv, nullptr, 2048, 4096, 2048);

    k_qkv_post<<<T_SEQ, b256, 0, stream>>>(qkv, qnw + (size_t)lyr * 128, knw + (size_t)lyr * 128, pos, qb, kb, vb);
    k_transpose_bf16<ushort_t><<<dim3(16, 32), b256, 0, stream>>>(vb, vT, 2048, 1024);
    k_flash<<<dim3(T_SEQ / 16, NH), b64, 0, stream>>>(qb, kb, vT, seg, ob);

    const float* wol = wo + (size_t)lyr * 2048 * DMODEL;
    k_transpose_bf16<float><<<dim3(32, 32), b256, 0, stream>>>(wol, wT, 2048, 2048);
    k_gemm<EPI_ADDRES><<<dim3(16, 16), b256, 0, stream>>>(ob, wT, xsrc, nullptr, out, nullptr, 2048, 2048, 2048);

    k_rmsnorm<1><<<T_SEQ, b256, 0, stream>>>(out, ln2 + (size_t)lyr * DMODEL, hbuf);

    const float* wgl = wg + (size_t)lyr * DMODEL * DFF;
    const float* wul = wu + (size_t)lyr * DMODEL * DFF;
    const float* wdl = wd + (size_t)lyr * DFF * DMODEL;
    k_transpose_bf16<float><<<dim3(128, 32), b256, 0, stream>>>(wgl, wT, 2048, 8192);
    k_gemm<EPI_STORE><<<dim3(64, 16), b256, 0, stream>>>(hbuf, wT, nullptr, nullptr, gbuf, nullptr, 2048, 8192, 2048);
    k_transpose_bf16<float><<<dim3(128, 32), b256, 0, stream>>>(wul, wT, 2048, 8192);
    k_gemm<EPI_SILU><<<dim3(64, 16), b256, 0, stream>>>(hbuf, wT, nullptr, gbuf, nullptr, mbuf, 2048, 8192, 2048);
    k_transpose_bf16<float><<<dim3(32, 128), b256, 0, stream>>>(wdl, wT, 8192, 2048);
    k_gemm<EPI_ADDRES><<<dim3(16, 16), b256, 0, stream>>>(mbuf, wT, out, nullptr, out, nullptr, 2048, 2048, 8192);
  }
  k_rmsnorm<0><<<T_SEQ, b256, 0, stream>>>(out, fnw, out);
}

// Round 2
// 1215.504 us; speedup vs baseline: 1.1314x; 1.1314x over previous
//
#include <hip/hip_runtime.h>
#include <stdint.h>

#define T_SEQ 2048
#define DMODEL 2048
#define NH 16
#define NKV 8
#define DHEAD 128
#define DFF 8192

typedef float f32x4 __attribute__((ext_vector_type(4)));
typedef float f32x2 __attribute__((ext_vector_type(2)));
typedef __bf16 bf16x8 __attribute__((ext_vector_type(8)));
typedef unsigned short ushort_t;

typedef __attribute__((address_space(1))) void gvoid;
typedef __attribute__((address_space(3))) void lvoid;

__device__ inline unsigned short f2bf(float f) {
  unsigned int u = __float_as_uint(f);
  u += 0x7fffu + ((u >> 16) & 1u);
  return (unsigned short)(u >> 16);
}
__device__ inline float bf2f(unsigned short h) {
  return __uint_as_float(((unsigned int)h) << 16);
}

__device__ inline void gload_lds16(const void* g, void* l) {
  // 16B per lane; LDS dest is wave-uniform base + lane*16 (HW rule)
  __builtin_amdgcn_global_load_lds((gvoid*)g, (lvoid*)l, 16, 0, 0);
}

// ---------------------------------------------------------------------------
// Transpose + convert: in f32/bf16 [R][C] -> out bf16 [C][R].  Tile 64x64.
// ---------------------------------------------------------------------------
template <typename TIN>
__global__ __launch_bounds__(256) void k_transpose_bf16(const TIN* __restrict__ in,
                                                        ushort_t* __restrict__ out,
                                                        int R, int C) {
  __shared__ float tile[64 * 72];
  int tid = threadIdx.x;
  int r0 = blockIdx.y * 64, c0 = blockIdx.x * 64;
  int rl = tid >> 4;   // 0..15
  int cc = tid & 15;   // 16B col chunk
#pragma unroll
  for (int i = 0; i < 4; ++i) {
    int row = rl + i * 16;
    const TIN* src = in + (size_t)(r0 + row) * C + c0 + cc * 4;
    float v0, v1, v2, v3;
    if constexpr (sizeof(TIN) == 4) {
      f32x4 v = *(const f32x4*)src;
      v0 = v.x; v1 = v.y; v2 = v.z; v3 = v.w;
    } else {
      ushort4 v = *(const ushort4*)src;
      v0 = bf2f(v.x); v1 = bf2f(v.y); v2 = bf2f(v.z); v3 = bf2f(v.w);
    }
    int chunk = cc ^ (row & 15);
    f32x4 t = {v0, v1, v2, v3};
    *(f32x4*)&tile[row * 72 + chunk * 4] = t;
  }
  __syncthreads();
#pragma unroll
  for (int i = 0; i < 4; ++i) {
    int nrow = rl + i * 16;   // output row local = input col
    int k4 = cc * 4;          // output col local base = input row
    ushort4 o;
    {
      int k = k4 + 0;
      o.x = f2bf(tile[k * 72 + (((nrow >> 2) ^ (k & 15)) << 2) + (nrow & 3)]);
      k = k4 + 1;
      o.y = f2bf(tile[k * 72 + (((nrow >> 2) ^ (k & 15)) << 2) + (nrow & 3)]);
      k = k4 + 2;
      o.z = f2bf(tile[k * 72 + (((nrow >> 2) ^ (k & 15)) << 2) + (nrow & 3)]);
      k = k4 + 3;
      o.w = f2bf(tile[k * 72 + (((nrow >> 2) ^ (k & 15)) << 2) + (nrow & 3)]);
    }
    *(ushort4*)(out + (size_t)(c0 + nrow) * R + r0 + k4) = o;
  }
}

// ---------------------------------------------------------------------------
// RMSNorm over D=2048, one block (256 thr) per row.
// ---------------------------------------------------------------------------
template <int BF16OUT>
__global__ __launch_bounds__(256) void k_rmsnorm(const float* __restrict__ X,
                                                 const float* __restrict__ W,
                                                 void* __restrict__ OUT) {
  int row = blockIdx.x, tid = threadIdx.x;
  const float* xr = X + (size_t)row * DMODEL;
  f32x4 x0 = *(const f32x4*)(xr + tid * 4);
  f32x4 x1 = *(const f32x4*)(xr + 1024 + tid * 4);
  float ss = x0.x * x0.x + x0.y * x0.y + x0.z * x0.z + x0.w * x0.w +
             x1.x * x1.x + x1.y * x1.y + x1.z * x1.z + x1.w * x1.w;
#pragma unroll
  for (int o = 1; o < 64; o <<= 1) ss += __shfl_xor(ss, o, 64);
  __shared__ float red[4];
  int w = tid >> 6;
  if ((tid & 63) == 0) red[w] = ss;
  __syncthreads();
  float tot = red[0] + red[1] + red[2] + red[3];
  float sc = rsqrtf(tot / (float)DMODEL + 1e-6f);
  f32x4 w0 = *(const f32x4*)(W + tid * 4);
  f32x4 w1 = *(const f32x4*)(W + 1024 + tid * 4);
  if constexpr (BF16OUT) {
    ushort_t* o = (ushort_t*)OUT + (size_t)row * DMODEL;
    ushort4 a, b;
    a.x = f2bf(x0.x * sc * w0.x); a.y = f2bf(x0.y * sc * w0.y);
    a.z = f2bf(x0.z * sc * w0.z); a.w = f2bf(x0.w * sc * w0.w);
    b.x = f2bf(x1.x * sc * w1.x); b.y = f2bf(x1.y * sc * w1.y);
    b.z = f2bf(x1.z * sc * w1.z); b.w = f2bf(x1.w * sc * w1.w);
    *(ushort4*)(o + tid * 4) = a;
    *(ushort4*)(o + 1024 + tid * 4) = b;
  } else {
    float* o = (float*)OUT + (size_t)row * DMODEL;
    f32x4 a = {x0.x * sc * w0.x, x0.y * sc * w0.y, x0.z * sc * w0.z, x0.w * sc * w0.w};
    f32x4 b = {x1.x * sc * w1.x, x1.y * sc * w1.y, x1.z * sc * w1.z, x1.w * sc * w1.w};
    *(f32x4*)(o + tid * 4) = a;
    *(f32x4*)(o + 1024 + tid * 4) = b;
  }
}

// ---------------------------------------------------------------------------
// Old 128x128 GEMM (kept for WO / WD).  EPI: 0 store f32, 1 f32+residual,
// 2 silu(GIN)*acc -> bf16.
// ---------------------------------------------------------------------------
#define EPI_STORE 0
#define EPI_ADDRES 1
#define EPI_SILU 2

template <int EPI>
__global__ __launch_bounds__(256) void k_gemm(const ushort_t* __restrict__ A,
                                              const ushort_t* __restrict__ BT,
                                              const float* __restrict__ RES,
                                              const float* __restrict__ GIN,
                                              float* __restrict__ CF,
                                              ushort_t* __restrict__ CB,
                                              int M, int N, int K) {
  __shared__ ushort_t As[128 * 32];
  __shared__ ushort_t Bs[128 * 32];
  int tid = threadIdx.x;
  int w = tid >> 6, l = tid & 63;
  int wm = w >> 1, wn = w & 1;
  int m0 = blockIdx.y * 128, n0 = blockIdx.x * 128;
  int lr = l & 15, lg = l >> 4;
  f32x4 acc[4][4] = {};
  for (int kt = 0; kt < K; kt += 32) {
#pragma unroll
    for (int it = 0; it < 2; ++it) {
      int idx = it * 256 + tid;
      int r = idx >> 2, c = idx & 3;
      gload_lds16(A + (size_t)(m0 + r) * K + kt + c * 8, &As[(it * 256 + w * 64) * 8]);
      gload_lds16(BT + (size_t)(n0 + r) * K + kt + c * 8, &Bs[(it * 256 + w * 64) * 8]);
    }
    __syncthreads();
    const bf16x8* Av = (const bf16x8*)As;
    const bf16x8* Bv = (const bf16x8*)Bs;
    bf16x8 af[4], bfr[4];
#pragma unroll
    for (int i = 0; i < 4; ++i) {
      af[i] = Av[(wm * 64 + i * 16 + lr) * 4 + lg];
      bfr[i] = Bv[(wn * 64 + i * 16 + lr) * 4 + lg];
    }
#pragma unroll
    for (int i = 0; i < 4; ++i)
#pragma unroll
      for (int j = 0; j < 4; ++j)
        acc[i][j] = __builtin_amdgcn_mfma_f32_16x16x32_bf16(af[i], bfr[j], acc[i][j], 0, 0, 0);
    __syncthreads();
  }
#pragma unroll
  for (int i = 0; i < 4; ++i)
#pragma unroll
    for (int j = 0; j < 4; ++j)
#pragma unroll
      for (int r = 0; r < 4; ++r) {
        int m = m0 + wm * 64 + i * 16 + lg * 4 + r;
        int n = n0 + wn * 64 + j * 16 + lr;
        size_t off = (size_t)m * N + n;
        float v = acc[i][j][r];
        if constexpr (EPI == EPI_STORE) {
          CF[off] = v;
        } else if constexpr (EPI == EPI_ADDRES) {
          CF[off] = v + RES[off];
        } else {
          float gv = GIN[off];
          float s = gv / (1.f + __expf(-gv));
          CB[off] = f2bf(s * v);
        }
      }
}

// ---------------------------------------------------------------------------
// 256x256 8-phase GEMM (T2 swizzle + T3/T4 counted vmcnt + T5 setprio).
// 8 waves 4Mx2N, BK=64, LDS 128KB double-buffered, 8 slots/tile of 64 rows.
// Stage order per tile t (for t+1): P0:A0,A1  P1:A2,A3  P2:B0,B2  P3:B1,B3.
// Waits: vmcnt(4) @P1 (drains prev B1,B3 before P2 reads),
//        vmcnt(2) @P3 (drains A0-A3,B0,B2 of next; keeps its B1,B3 in flight).
// LDS swizzle: 16B chunk c of row r stored at c^(r&7); pre-swizzled source.
// ---------------------------------------------------------------------------
#define LOAD_B256(bs, rbase)                                                   \
  {                                                                            \
    _Pragma("unroll") for (int ks = 0; ks < 2; ++ks)                           \
        _Pragma("unroll") for (int ni = 0; ni < 2; ++ni)                       \
            bfr[ks][ni] = *(const bf16x8*)((bs) +                              \
                (((rbase) + ni * 16 + lr) << 6) +                              \
                ((((ks << 2) + lg) ^ (lr & 7)) << 3));                         \
  }

#define MFMA_Q256(q)                                                           \
  {                                                                            \
    _Pragma("unroll") for (int ks = 0; ks < 2; ++ks)                           \
        _Pragma("unroll") for (int mi = 0; mi < 4; ++mi)                       \
            _Pragma("unroll") for (int ni = 0; ni < 2; ++ni)                   \
                acc[mi][(q) * 2 + ni] =                                        \
                    __builtin_amdgcn_mfma_f32_16x16x32_bf16(                   \
                        af[ks][mi], bfr[ks][ni], acc[mi][(q) * 2 + ni], 0, 0, 0); \
  }

template <int EPI>
__global__ __launch_bounds__(512, 2) void k_gemm256(
    const ushort_t* __restrict__ A, const ushort_t* __restrict__ BT,
    const float* __restrict__ GIN, float* __restrict__ CF,
    ushort_t* __restrict__ CB, int M, int N, int K) {
  __shared__ ushort_t lds[65536];  // 128 KiB
  const int tid = threadIdx.x;
  const int l = tid & 63, wid = tid >> 6;
  const int wm = wid >> 1, wn = wid & 1;
  const int lr = l & 15, lg = l >> 4;
  const int m0 = blockIdx.y * 256, n0 = blockIdx.x * 256;
  const int NT = K >> 6;

  const int srow = tid >> 3;                    // 0..63 row within a slot
  const int scs = (tid & 7) ^ (srow & 7);       // pre-swizzled source chunk
  const size_t sgoff = (size_t)srow * K + scs * 8;
  const int slds = wid * 512;                   // wave-uniform ushort offset

  const ushort_t* ga = A + (size_t)m0 * K + sgoff;
  const ushort_t* gb = BT + (size_t)n0 * K + sgoff;
  const size_t rs = (size_t)64 * K;             // 64-row stride (elements)

  f32x4 acc[4][8] = {};

  ushort_t* Ab0 = lds;
  ushort_t* Bb0 = lds + 16384;
  ushort_t* Ab1 = lds + 32768;
  ushort_t* Bb1 = lds + 49152;

  // prologue: tile0 -> dbuf0, issue order A0,A1,A2,A3,B0,B2,B1,B3
  gload_lds16(ga, Ab0 + slds);
  gload_lds16(ga + rs, Ab0 + 4096 + slds);
  gload_lds16(ga + 2 * rs, Ab0 + 8192 + slds);
  gload_lds16(ga + 3 * rs, Ab0 + 12288 + slds);
  gload_lds16(gb, Bb0 + slds);
  gload_lds16(gb + 2 * rs, Bb0 + 8192 + slds);
  gload_lds16(gb + rs, Bb0 + 4096 + slds);
  gload_lds16(gb + 3 * rs, Bb0 + 12288 + slds);
  asm volatile("s_waitcnt vmcnt(2)" ::: "memory");
  __builtin_amdgcn_s_barrier();

  for (int kt = 0; kt < NT; ++kt) {
    const bool last = (kt == NT - 1);
    const int d = kt & 1;
    const ushort_t* as = (d ? Ab1 : Ab0) + wm * 4096;
    const ushort_t* bsA = (d ? Bb1 : Bb0) + (wn * 2) * 4096;
    const ushort_t* bsB = bsA + 4096;
    ushort_t* nA = d ? Ab0 : Ab1;
    ushort_t* nB = d ? Bb0 : Bb1;
    const ushort_t* an = ga + (size_t)(kt + 1) * 64;
    const ushort_t* bn = gb + (size_t)(kt + 1) * 64;

    bf16x8 af[2][4], bfr[2][2];
    // ---- P0: all A frags + B cols 0..31 of slot pair lo ----
#pragma unroll
    for (int ks = 0; ks < 2; ++ks)
#pragma unroll
      for (int mi = 0; mi < 4; ++mi)
        af[ks][mi] = *(const bf16x8*)(as + ((mi * 16 + lr) << 6) +
                                      ((((ks << 2) + lg) ^ (lr & 7)) << 3));
    LOAD_B256(bsA, 0);
    if (!last) {
      gload_lds16(an, nA + slds);
      gload_lds16(an + rs, nA + 4096 + slds);
    }
    __builtin_amdgcn_s_barrier();
    asm volatile("s_waitcnt lgkmcnt(0)" ::: "memory");
    __builtin_amdgcn_sched_barrier(0);
    __builtin_amdgcn_s_setprio(1);
    MFMA_Q256(0);
    __builtin_amdgcn_s_setprio(0);
    __builtin_amdgcn_s_barrier();
    // ---- P1 ----
    LOAD_B256(bsA, 32);
    if (!last) {
      gload_lds16(an + 2 * rs, nA + 8192 + slds);
      gload_lds16(an + 3 * rs, nA + 12288 + slds);
      asm volatile("s_waitcnt vmcnt(4)" ::: "memory");
    } else {
      asm volatile("s_waitcnt vmcnt(0)" ::: "memory");
    }
    __builtin_amdgcn_s_barrier();
    asm volatile("s_waitcnt lgkmcnt(0)" ::: "memory");
    __builtin_amdgcn_sched_barrier(0);
    __builtin_amdgcn_s_setprio(1);
    MFMA_Q256(1);
    __builtin_amdgcn_s_setprio(0);
    __builtin_amdgcn_s_barrier();
    // ---- P2 ----
    LOAD_B256(bsB, 0);
    if (!last) {
      gload_lds16(bn, nB + slds);
      gload_lds16(bn + 2 * rs, nB + 8192 + slds);
    }
    __builtin_amdgcn_s_barrier();
    asm volatile("s_waitcnt lgkmcnt(0)" ::: "memory");
    __builtin_amdgcn_sched_barrier(0);
    __builtin_amdgcn_s_setprio(1);
    MFMA_Q256(2);
    __builtin_amdgcn_s_setprio(0);
    __builtin_amdgcn_s_barrier();
    // ---- P3 ----
    LOAD_B256(bsB, 32);
    if (!last) {
      gload_lds16(bn + rs, nB + 4096 + slds);
      gload_lds16(bn + 3 * rs, nB + 12288 + slds);
      asm volatile("s_waitcnt vmcnt(2)" ::: "memory");
    }
    __builtin_amdgcn_s_barrier();
    asm volatile("s_waitcnt lgkmcnt(0)" ::: "memory");
    __builtin_amdgcn_sched_barrier(0);
    __builtin_amdgcn_s_setprio(1);
    MFMA_Q256(3);
    __builtin_amdgcn_s_setprio(0);
    __builtin_amdgcn_s_barrier();
  }

  // epilogue
#pragma unroll
  for (int mi = 0; mi < 4; ++mi)
#pragma unroll
    for (int ci = 0; ci < 8; ++ci)
#pragma unroll
      for (int rr = 0; rr < 4; ++rr) {
        int m = m0 + wm * 64 + mi * 16 + lg * 4 + rr;
        int n = n0 + wn * 128 + ci * 16 + lr;
        size_t off = (size_t)m * N + n;
        float v = acc[mi][ci][rr];
        if constexpr (EPI == EPI_STORE) {
          CF[off] = v;
        } else {
          float gv = GIN[off];
          float s = gv / (1.f + __expf(-gv));
          CB[off] = f2bf(s * v);
        }
      }
  (void)M;
}

// ---------------------------------------------------------------------------
// Post-QKV: per-head RMSNorm (q,k) + RoPE + bf16 cast.
// ---------------------------------------------------------------------------
__global__ __launch_bounds__(256) void k_qkv_post(const float* __restrict__ QKV,
                                                  const float* __restrict__ QNW,
                                                  const float* __restrict__ KNW,
                                                  const int* __restrict__ POS,
                                                  ushort_t* __restrict__ Qb,
                                                  ushort_t* __restrict__ Kb,
                                                  ushort_t* __restrict__ Vb) {
  int t = blockIdx.x;
  int tid = threadIdx.x;
  int w = tid >> 6, l = tid & 63;
  float pos = (float)POS[t];
  const float* base = QKV + (size_t)t * 4096;
  int i0 = 2 * (l & 31);
  const float K2 = 19.931568569324174f / 64.f;  // log2(1e6)/64
  float ang0 = pos * exp2f(-(float)i0 * K2);
  float ang1 = pos * exp2f(-(float)(i0 + 1) * K2);
  float cs0 = cosf(ang0), sn0 = sinf(ang0);
  float cs1 = cosf(ang1), sn1 = sinf(ang1);
#pragma unroll
  for (int si = 0; si < 8; ++si) {
    int slot = w + si * 4;
    const float* p = base + slot * 128;
    f32x2 xv = *(const f32x2*)(p + l * 2);
    float v0 = xv.x, v1 = xv.y;
    float ss = v0 * v0 + v1 * v1;
#pragma unroll
    for (int o = 1; o < 64; o <<= 1) ss += __shfl_xor(ss, o, 64);
    if (slot < 24) {
      float sc = rsqrtf(ss / 128.f + 1e-6f);
      const float* wn = (slot < 16) ? QNW : KNW;
      f32x2 wv = *(const f32x2*)(wn + l * 2);
      v0 = v0 * sc * wv.x;
      v1 = v1 * sc * wv.y;
      float p0 = __shfl_xor(v0, 32, 64);
      float p1 = __shfl_xor(v1, 32, 64);
      float r0 = (l < 32) ? -p0 : p0;
      float r1 = (l < 32) ? -p1 : p1;
      v0 = v0 * cs0 + r0 * sn0;
      v1 = v1 * cs1 + r1 * sn1;
    }
    ushort2 uv;
    uv.x = f2bf(v0);
    uv.y = f2bf(v1);
    ushort_t* dst;
    if (slot < 16)
      dst = Qb + (size_t)t * 2048 + slot * 128 + l * 2;
    else if (slot < 24)
      dst = Kb + (size_t)t * 1024 + (slot - 16) * 128 + l * 2;
    else
      dst = Vb + (size_t)t * 1024 + (slot - 24) * 128 + l * 2;
    *(ushort2*)dst = uv;
  }
}

// ---------------------------------------------------------------------------
// Flash attention, ragged causal (segment) mask.  1 wave per (16 q rows, head).
// ---------------------------------------------------------------------------
__global__ __launch_bounds__(64) void k_flash(const ushort_t* __restrict__ Qb,
                                              const ushort_t* __restrict__ Kb,
                                              const ushort_t* __restrict__ VT,
                                              const int* __restrict__ SEG,
                                              ushort_t* __restrict__ Ob) {
  __shared__ ushort_t Pl[16 * 40];
  int l = threadIdx.x;
  int qt = blockIdx.x, h = blockIdx.y;
  int q0 = qt * 16;
  int lr = l & 15, lg = l >> 4;
  int kvh = h >> 1;
  bf16x8 qf[4];
  {
    const bf16x8* qv = (const bf16x8*)(Qb + (size_t)(q0 + lr) * 2048 + h * 128);
#pragma unroll
    for (int kk = 0; kk < 4; ++kk) qf[kk] = qv[kk * 4 + lg];
  }
  int segq[4];
#pragma unroll
  for (int r = 0; r < 4; ++r) segq[r] = SEG[q0 + lg * 4 + r];
  int target = SEG[q0];
  int lo = 0, hi = q0;
  while (lo < hi) {
    int mid = (lo + hi) >> 1;
    if (SEG[mid] < target) lo = mid + 1; else hi = mid;
  }
  int s_start = lo & ~31;
  float m_run[4], l_run[4];
  f32x4 acc[8] = {};
#pragma unroll
  for (int r = 0; r < 4; ++r) { m_run[r] = -1e30f; l_run[r] = 0.f; }
  const float scale = 0.08838834764831845f;  // 1/sqrt(128)
  for (int s0 = s_start; s0 < q0 + 16; s0 += 32) {
    int sa = s0 + lr, sb = s0 + 16 + lr;
    int sac = min(sa, T_SEQ - 1), sbc = min(sb, T_SEQ - 1);
    f32x4 SA = {}, SB = {};
    const bf16x8* ka = (const bf16x8*)(Kb + (size_t)sac * 1024 + kvh * 128);
    const bf16x8* kb = (const bf16x8*)(Kb + (size_t)sbc * 1024 + kvh * 128);
#pragma unroll
    for (int kk = 0; kk < 4; ++kk) {
      SA = __builtin_amdgcn_mfma_f32_16x16x32_bf16(qf[kk], ka[kk * 4 + lg], SA, 0, 0, 0);
      SB = __builtin_amdgcn_mfma_f32_16x16x32_bf16(qf[kk], kb[kk * 4 + lg], SB, 0, 0, 0);
    }
    int sga = SEG[sac], sgb = SEG[sbc];
    float al[4], pA[4], pB[4];
#pragma unroll
    for (int r = 0; r < 4; ++r) {
      int qrow = q0 + lg * 4 + r;
      float xa = (sa <= qrow && sga == segq[r]) ? SA[r] * scale : -1e30f;
      float xb = (sb <= qrow && sgb == segq[r]) ? SB[r] * scale : -1e30f;
      float mx = fmaxf(xa, xb);
#pragma unroll
      for (int o = 1; o < 16; o <<= 1) mx = fmaxf(mx, __shfl_xor(mx, o, 64));
      float nm = fmaxf(m_run[r], mx);
      float ea = __expf(xa - nm), eb = __expf(xb - nm);
      float rs = ea + eb;
#pragma unroll
      for (int o = 1; o < 16; o <<= 1) rs += __shfl_xor(rs, o, 64);
      al[r] = __expf(m_run[r] - nm);
      l_run[r] = l_run[r] * al[r] + rs;
      m_run[r] = nm;
      pA[r] = ea;
      pB[r] = eb;
    }
#pragma unroll
    for (int c = 0; c < 8; ++c)
#pragma unroll
      for (int r = 0; r < 4; ++r) acc[c][r] *= al[r];
    __syncthreads();
#pragma unroll
    for (int r = 0; r < 4; ++r) {
      Pl[(lg * 4 + r) * 40 + lr] = f2bf(pA[r]);
      Pl[(lg * 4 + r) * 40 + 16 + lr] = f2bf(pB[r]);
    }
    __syncthreads();
    bf16x8 pa = *(const bf16x8*)&Pl[lr * 40 + lg * 8];
    int sbase = min(s0 + lg * 8, T_SEQ - 8);
#pragma unroll
    for (int c = 0; c < 8; ++c) {
      bf16x8 vb = *(const bf16x8*)(VT + (size_t)(kvh * 128 + c * 16 + lr) * T_SEQ + sbase);
      acc[c] = __builtin_amdgcn_mfma_f32_16x16x32_bf16(pa, vb, acc[c], 0, 0, 0);
    }
  }
#pragma unroll
  for (int c = 0; c < 8; ++c)
#pragma unroll
    for (int r = 0; r < 4; ++r) {
      float ov = acc[c][r] / l_run[r];
      Ob[(size_t)(q0 + lg * 4 + r) * 2048 + h * 128 + c * 16 + lr] = f2bf(ov);
    }
}

// ---------------------------------------------------------------------------
extern "C" void kernel_launch(void* const* d_in, const int* in_sizes, int n_in,
                              void* d_out, int out_size, void* d_ws, size_t ws_size,
                              hipStream_t stream) {
  const float* hidden = (const float*)d_in[0];
  const float* ln1 = (const float*)d_in[1];
  const float* ln2 = (const float*)d_in[2];
  const float* wq = (const float*)d_in[3];
  const float* wk = (const float*)d_in[4];
  const float* wv = (const float*)d_in[5];
  const float* wo = (const float*)d_in[6];
  const float* qnw = (const float*)d_in[7];
  const float* knw = (const float*)d_in[8];
  const float* wg = (const float*)d_in[9];
  const float* wu = (const float*)d_in[10];
  const float* wd = (const float*)d_in[11];
  const float* fnw = (const float*)d_in[12];
  const int* seg = (const int*)d_in[13];
  const int* pos = (const int*)d_in[14];
  float* out = (float*)d_out;

  char* ws = (char*)d_ws;
  size_t off = 0;
  auto alloc = [&](size_t bytes) {
    char* p = ws + off;
    off += (bytes + 255) & ~(size_t)255;
    return p;
  };
  ushort_t* wT = (ushort_t*)alloc((size_t)DFF * DMODEL * 2);       // rotating
  ushort_t* hbuf = (ushort_t*)alloc((size_t)T_SEQ * DMODEL * 2);
  float* qkv = (float*)alloc((size_t)T_SEQ * 4096 * 4);
  ushort_t* qb = (ushort_t*)alloc((size_t)T_SEQ * 2048 * 2);
  ushort_t* kb = (ushort_t*)alloc((size_t)T_SEQ * 1024 * 2);
  ushort_t* vb = (ushort_t*)alloc((size_t)T_SEQ * 1024 * 2);
  ushort_t* vT = (ushort_t*)alloc((size_t)T_SEQ * 1024 * 2);
  ushort_t* ob = (ushort_t*)alloc((size_t)T_SEQ * 2048 * 2);
  float* gbuf = (float*)alloc((size_t)T_SEQ * DFF * 4);
  ushort_t* mbuf = (ushort_t*)alloc((size_t)T_SEQ * DFF * 2);
  (void)ws_size; (void)in_sizes; (void)n_in; (void)out_size;

  dim3 b256(256), b64(64), b512(512);
  for (int lyr = 0; lyr < 2; ++lyr) {
    const float* xsrc = (lyr == 0) ? hidden : out;
    k_rmsnorm<1><<<T_SEQ, b256, 0, stream>>>(xsrc, ln1 + (size_t)lyr * DMODEL, hbuf);

    const float* wql = wq + (size_t)lyr * DMODEL * 2048;
    const float* wkl = wk + (size_t)lyr * DMODEL * 1024;
    const float* wvl = wv + (size_t)lyr * DMODEL * 1024;
    k_transpose_bf16<float><<<dim3(32, 32), b256, 0, stream>>>(wql, wT, 2048, 2048);
    k_transpose_bf16<float><<<dim3(16, 32), b256, 0, stream>>>(wkl, wT + (size_t)2048 * 2048, 2048, 1024);
    k_transpose_bf16<float><<<dim3(16, 32), b256, 0, stream>>>(wvl, wT + (size_t)3072 * 2048, 2048, 1024);
    k_gemm256<EPI_STORE><<<dim3(16, 8), b512, 0, stream>>>(hbuf, wT, nullptr, qkv, nullptr, 2048, 4096, 2048);

    k_qkv_post<<<T_SEQ, b256, 0, stream>>>(qkv, qnw + (size_t)lyr * 128, knw + (size_t)lyr * 128, pos, qb, kb, vb);
    k_transpose_bf16<ushort_t><<<dim3(16, 32), b256, 0, stream>>>(vb, vT, 2048, 1024);
    k_flash<<<dim3(T_SEQ / 16, NH), b64, 0, stream>>>(qb, kb, vT, seg, ob);

    const float* wol = wo + (size_t)lyr * 2048 * DMODEL;
    k_transpose_bf16<float><<<dim3(32, 32), b256, 0, stream>>>(wol, wT, 2048, 2048);
    k_gemm<EPI_ADDRES><<<dim3(16, 16), b256, 0, stream>>>(ob, wT, xsrc, nullptr, out, nullptr, 2048, 2048, 2048);

    k_rmsnorm<1><<<T_SEQ, b256, 0, stream>>>(out, ln2 + (size_t)lyr * DMODEL, hbuf);

    const float* wgl = wg + (size_t)lyr * DMODEL * DFF;
    const float* wul = wu + (size_t)lyr * DMODEL * DFF;
    const float* wdl = wd + (size_t)lyr * DFF * DMODEL;
    k_transpose_bf16<float><<<dim3(128, 32), b256, 0, stream>>>(wgl, wT, 2048, 8192);
    k_gemm256<EPI_STORE><<<dim3(32, 8), b512, 0, stream>>>(hbuf, wT, nullptr, gbuf, nullptr, 2048, 8192, 2048);
    k_transpose_bf16<float><<<dim3(128, 32), b256, 0, stream>>>(wul, wT, 2048, 8192);
    k_gemm256<EPI_SILU><<<dim3(32, 8), b512, 0, stream>>>(hbuf, wT, gbuf, nullptr, mbuf, 2048, 8192, 2048);
    k_transpose_bf16<float><<<dim3(32, 128), b256, 0, stream>>>(wdl, wT, 8192, 2048);
    k_gemm<EPI_ADDRES><<<dim3(16, 16), b256, 0, stream>>>(mbuf, wT, out, nullptr, out, nullptr, 2048, 2048, 8192);
  }
  k_rmsnorm<0><<<T_SEQ, b256, 0, stream>>>(out, fnw, out);
}

// Round 4
// 986.000 us; speedup vs baseline: 1.3948x; 1.2328x over previous
//
#include <hip/hip_runtime.h>
#include <stdint.h>

#define T_SEQ 2048
#define DMODEL 2048
#define NH 16
#define NKV 8
#define DHEAD 128
#define DFF 8192

typedef float f32x4 __attribute__((ext_vector_type(4)));
typedef float f32x2 __attribute__((ext_vector_type(2)));
typedef __bf16 bf16x8 __attribute__((ext_vector_type(8)));
typedef unsigned short ushort_t;

typedef __attribute__((address_space(1))) void gvoid;
typedef __attribute__((address_space(3))) void lvoid;

__device__ inline unsigned short f2bf(float f) {
  unsigned int u = __float_as_uint(f);
  u += 0x7fffu + ((u >> 16) & 1u);
  return (unsigned short)(u >> 16);
}
__device__ inline float bf2f(unsigned short h) {
  return __uint_as_float(((unsigned int)h) << 16);
}

__device__ inline void gload_lds16(const void* g, void* l) {
  // 16B per lane; LDS dest is wave-uniform base + lane*16 (HW rule)
  __builtin_amdgcn_global_load_lds((gvoid*)g, (lvoid*)l, 16, 0, 0);
}

// ---------------------------------------------------------------------------
// Transpose + convert: in f32/bf16 [R][C] -> out bf16 [C][R].  Tile 64x64.
// ---------------------------------------------------------------------------
template <typename TIN>
__global__ __launch_bounds__(256) void k_transpose_bf16(const TIN* __restrict__ in,
                                                        ushort_t* __restrict__ out,
                                                        int R, int C) {
  __shared__ float tile[64 * 72];
  int tid = threadIdx.x;
  int r0 = blockIdx.y * 64, c0 = blockIdx.x * 64;
  int rl = tid >> 4;   // 0..15
  int cc = tid & 15;   // 16B col chunk
#pragma unroll
  for (int i = 0; i < 4; ++i) {
    int row = rl + i * 16;
    const TIN* src = in + (size_t)(r0 + row) * C + c0 + cc * 4;
    float v0, v1, v2, v3;
    if constexpr (sizeof(TIN) == 4) {
      f32x4 v = *(const f32x4*)src;
      v0 = v.x; v1 = v.y; v2 = v.z; v3 = v.w;
    } else {
      ushort4 v = *(const ushort4*)src;
      v0 = bf2f(v.x); v1 = bf2f(v.y); v2 = bf2f(v.z); v3 = bf2f(v.w);
    }
    int chunk = cc ^ (row & 15);
    f32x4 t = {v0, v1, v2, v3};
    *(f32x4*)&tile[row * 72 + chunk * 4] = t;
  }
  __syncthreads();
#pragma unroll
  for (int i = 0; i < 4; ++i) {
    int nrow = rl + i * 16;   // output row local = input col
    int k4 = cc * 4;          // output col local base = input row
    ushort4 o;
    {
      int k = k4 + 0;
      o.x = f2bf(tile[k * 72 + (((nrow >> 2) ^ (k & 15)) << 2) + (nrow & 3)]);
      k = k4 + 1;
      o.y = f2bf(tile[k * 72 + (((nrow >> 2) ^ (k & 15)) << 2) + (nrow & 3)]);
      k = k4 + 2;
      o.z = f2bf(tile[k * 72 + (((nrow >> 2) ^ (k & 15)) << 2) + (nrow & 3)]);
      k = k4 + 3;
      o.w = f2bf(tile[k * 72 + (((nrow >> 2) ^ (k & 15)) << 2) + (nrow & 3)]);
    }
    *(ushort4*)(out + (size_t)(c0 + nrow) * R + r0 + k4) = o;
  }
}

// ---------------------------------------------------------------------------
// RMSNorm over D=2048, one block (256 thr) per row.
// ---------------------------------------------------------------------------
template <int BF16OUT>
__global__ __launch_bounds__(256) void k_rmsnorm(const float* __restrict__ X,
                                                 const float* __restrict__ W,
                                                 void* __restrict__ OUT) {
  int row = blockIdx.x, tid = threadIdx.x;
  const float* xr = X + (size_t)row * DMODEL;
  f32x4 x0 = *(const f32x4*)(xr + tid * 4);
  f32x4 x1 = *(const f32x4*)(xr + 1024 + tid * 4);
  float ss = x0.x * x0.x + x0.y * x0.y + x0.z * x0.z + x0.w * x0.w +
             x1.x * x1.x + x1.y * x1.y + x1.z * x1.z + x1.w * x1.w;
#pragma unroll
  for (int o = 1; o < 64; o <<= 1) ss += __shfl_xor(ss, o, 64);
  __shared__ float red[4];
  int w = tid >> 6;
  if ((tid & 63) == 0) red[w] = ss;
  __syncthreads();
  float tot = red[0] + red[1] + red[2] + red[3];
  float sc = rsqrtf(tot / (float)DMODEL + 1e-6f);
  f32x4 w0 = *(const f32x4*)(W + tid * 4);
  f32x4 w1 = *(const f32x4*)(W + 1024 + tid * 4);
  if constexpr (BF16OUT) {
    ushort_t* o = (ushort_t*)OUT + (size_t)row * DMODEL;
    ushort4 a, b;
    a.x = f2bf(x0.x * sc * w0.x); a.y = f2bf(x0.y * sc * w0.y);
    a.z = f2bf(x0.z * sc * w0.z); a.w = f2bf(x0.w * sc * w0.w);
    b.x = f2bf(x1.x * sc * w1.x); b.y = f2bf(x1.y * sc * w1.y);
    b.z = f2bf(x1.z * sc * w1.z); b.w = f2bf(x1.w * sc * w1.w);
    *(ushort4*)(o + tid * 4) = a;
    *(ushort4*)(o + 1024 + tid * 4) = b;
  } else {
    float* o = (float*)OUT + (size_t)row * DMODEL;
    f32x4 a = {x0.x * sc * w0.x, x0.y * sc * w0.y, x0.z * sc * w0.z, x0.w * sc * w0.w};
    f32x4 b = {x1.x * sc * w1.x, x1.y * sc * w1.y, x1.z * sc * w1.z, x1.w * sc * w1.w};
    *(f32x4*)(o + tid * 4) = a;
    *(f32x4*)(o + 1024 + tid * 4) = b;
  }
}

// ---------------------------------------------------------------------------
// Reduce 4 split-K partials + residual: OUT[i] = RES[i] + sum_z P[z*n + i]
// ---------------------------------------------------------------------------
__global__ __launch_bounds__(256) void k_red4res(const float* __restrict__ P,
                                                 const float* __restrict__ RES,
                                                 float* __restrict__ OUT, int n) {
  int i = (blockIdx.x * 256 + threadIdx.x) * 4;
  if (i >= n) return;
  f32x4 v = *(const f32x4*)(RES + i);
#pragma unroll
  for (int z = 0; z < 4; ++z) {
    f32x4 t = *(const f32x4*)(P + (size_t)z * n + i);
    v.x += t.x; v.y += t.y; v.z += t.z; v.w += t.w;
  }
  *(f32x4*)(OUT + i) = v;
}

// ---------------------------------------------------------------------------
// 256x256 8-phase GEMM (T2 swizzle + T3/T4 counted vmcnt + T5 setprio).
// 8 waves 4Mx2N, BK=64, LDS 128KB double-buffered, 8 slots/tile of 64 rows.
// Stage order per tile t (for t+1): P0:A0,A1  P1:A2,A3  P2:B0,B2  P3:B1,B3.
// Waits: vmcnt(4) @P1 (drains prev B1,B3 before P2 reads),
//        vmcnt(2) @P3 (drains A0-A3,B0,B2 of next; keeps its B1,B3 in flight).
// LDS swizzle: 16B chunk c of row r stored at c^(r&7); pre-swizzled source.
// Split-K via blockIdx.z: each z handles Kc columns, writes partial CF+z*zoff.
// EPI: 0 store f32, 2 silu(GINB bf16)*acc -> bf16, 3 store bf16.
// ---------------------------------------------------------------------------
#define EPI_STORE 0
#define EPI_SILU 2
#define EPI_STOREB 3

#define LOAD_B256(bs, rbase)                                                   \
  {                                                                            \
    _Pragma("unroll") for (int ks = 0; ks < 2; ++ks)                           \
        _Pragma("unroll") for (int ni = 0; ni < 2; ++ni)                       \
            bfr[ks][ni] = *(const bf16x8*)((bs) +                              \
                (((rbase) + ni * 16 + lr) << 6) +                              \
                ((((ks << 2) + lg) ^ (lr & 7)) << 3));                         \
  }

#define MFMA_Q256(q)                                                           \
  {                                                                            \
    _Pragma("unroll") for (int ks = 0; ks < 2; ++ks)                           \
        _Pragma("unroll") for (int mi = 0; mi < 4; ++mi)                       \
            _Pragma("unroll") for (int ni = 0; ni < 2; ++ni)                   \
                acc[mi][(q) * 2 + ni] =                                        \
                    __builtin_amdgcn_mfma_f32_16x16x32_bf16(                   \
                        af[ks][mi], bfr[ks][ni], acc[mi][(q) * 2 + ni], 0, 0, 0); \
  }

template <int LAST>
__device__ __forceinline__ void g256_iter(
    const ushort_t* __restrict__ as, const ushort_t* __restrict__ bsA,
    const ushort_t* __restrict__ bsB, ushort_t* __restrict__ nA,
    ushort_t* __restrict__ nB, const ushort_t* __restrict__ an,
    const ushort_t* __restrict__ bn, size_t rs, int slds, int lr, int lg,
    f32x4 (&acc)[4][8]) {
  bf16x8 af[2][4], bfr[2][2];
  // ---- P0: all A frags + B rows 0..31 of low slot ----
#pragma unroll
  for (int ks = 0; ks < 2; ++ks)
#pragma unroll
    for (int mi = 0; mi < 4; ++mi)
      af[ks][mi] = *(const bf16x8*)(as + ((mi * 16 + lr) << 6) +
                                    ((((ks << 2) + lg) ^ (lr & 7)) << 3));
  LOAD_B256(bsA, 0);
  if constexpr (!LAST) {
    gload_lds16(an, nA + slds);
    gload_lds16(an + rs, nA + 4096 + slds);
  }
  __builtin_amdgcn_s_barrier();
  asm volatile("s_waitcnt lgkmcnt(0)" ::: "memory");
  __builtin_amdgcn_sched_barrier(0);
  __builtin_amdgcn_s_setprio(1);
  MFMA_Q256(0);
  __builtin_amdgcn_s_setprio(0);
  __builtin_amdgcn_s_barrier();
  // ---- P1 ----
  LOAD_B256(bsA, 32);
  if constexpr (!LAST) {
    gload_lds16(an + 2 * rs, nA + 8192 + slds);
    gload_lds16(an + 3 * rs, nA + 12288 + slds);
    asm volatile("s_waitcnt vmcnt(4)" ::: "memory");
  } else {
    asm volatile("s_waitcnt vmcnt(0)" ::: "memory");
  }
  __builtin_amdgcn_s_barrier();
  asm volatile("s_waitcnt lgkmcnt(0)" ::: "memory");
  __builtin_amdgcn_sched_barrier(0);
  __builtin_amdgcn_s_setprio(1);
  MFMA_Q256(1);
  __builtin_amdgcn_s_setprio(0);
  __builtin_amdgcn_s_barrier();
  // ---- P2 ----
  LOAD_B256(bsB, 0);
  if constexpr (!LAST) {
    gload_lds16(bn, nB + slds);
    gload_lds16(bn + 2 * rs, nB + 8192 + slds);
  }
  __builtin_amdgcn_s_barrier();
  asm volatile("s_waitcnt lgkmcnt(0)" ::: "memory");
  __builtin_amdgcn_sched_barrier(0);
  __builtin_amdgcn_s_setprio(1);
  MFMA_Q256(2);
  __builtin_amdgcn_s_setprio(0);
  __builtin_amdgcn_s_barrier();
  // ---- P3 ----
  LOAD_B256(bsB, 32);
  if constexpr (!LAST) {
    gload_lds16(bn + rs, nB + 4096 + slds);
    gload_lds16(bn + 3 * rs, nB + 12288 + slds);
    asm volatile("s_waitcnt vmcnt(2)" ::: "memory");
  }
  __builtin_amdgcn_s_barrier();
  asm volatile("s_waitcnt lgkmcnt(0)" ::: "memory");
  __builtin_amdgcn_sched_barrier(0);
  __builtin_amdgcn_s_setprio(1);
  MFMA_Q256(3);
  __builtin_amdgcn_s_setprio(0);
  __builtin_amdgcn_s_barrier();
}

template <int EPI>
__global__ __launch_bounds__(512, 2) void k_gemm256(
    const ushort_t* __restrict__ A, const ushort_t* __restrict__ BT,
    const ushort_t* __restrict__ GINB, float* __restrict__ CF,
    ushort_t* __restrict__ CB, int N, int Kstride, int Kc, size_t zoff) {
  __shared__ ushort_t lds[65536];  // 128 KiB
  const int tid = threadIdx.x;
  const int l = tid & 63, wid = tid >> 6;
  const int wm = wid >> 1, wn = wid & 1;
  const int lr = l & 15, lg = l >> 4;
  const int m0 = blockIdx.y * 256, n0 = blockIdx.x * 256;
  const int z = blockIdx.z;
  const int NT = Kc >> 6;

  A += (size_t)z * Kc;
  BT += (size_t)z * Kc;
  CF += (size_t)z * zoff;

  const int srow = tid >> 3;                    // 0..63 row within a slot
  const int scs = (tid & 7) ^ (srow & 7);       // pre-swizzled source chunk
  const size_t sgoff = (size_t)srow * Kstride + scs * 8;
  const int slds = wid * 512;                   // wave-uniform ushort offset

  const ushort_t* ga = A + (size_t)m0 * Kstride + sgoff;
  const ushort_t* gb = BT + (size_t)n0 * Kstride + sgoff;
  const size_t rs = (size_t)64 * Kstride;       // 64-row stride (elements)

  f32x4 acc[4][8] = {};

  ushort_t* Ab0 = lds;
  ushort_t* Bb0 = lds + 16384;
  ushort_t* Ab1 = lds + 32768;
  ushort_t* Bb1 = lds + 49152;

  // prologue: tile0 -> dbuf0, issue order A0,A1,A2,A3,B0,B2,B1,B3
  gload_lds16(ga, Ab0 + slds);
  gload_lds16(ga + rs, Ab0 + 4096 + slds);
  gload_lds16(ga + 2 * rs, Ab0 + 8192 + slds);
  gload_lds16(ga + 3 * rs, Ab0 + 12288 + slds);
  gload_lds16(gb, Bb0 + slds);
  gload_lds16(gb + 2 * rs, Bb0 + 8192 + slds);
  gload_lds16(gb + rs, Bb0 + 4096 + slds);
  gload_lds16(gb + 3 * rs, Bb0 + 12288 + slds);
  asm volatile("s_waitcnt vmcnt(2)" ::: "memory");
  __builtin_amdgcn_s_barrier();

  for (int kt = 0; kt < NT - 1; ++kt) {
    const int d = kt & 1;
    const ushort_t* as = (d ? Ab1 : Ab0) + wm * 4096;
    const ushort_t* bsA = (d ? Bb1 : Bb0) + (wn * 2) * 4096;
    ushort_t* nA = d ? Ab0 : Ab1;
    ushort_t* nB = d ? Bb0 : Bb1;
    g256_iter<0>(as, bsA, bsA + 4096, nA, nB, ga + (size_t)(kt + 1) * 64,
                 gb + (size_t)(kt + 1) * 64, rs, slds, lr, lg, acc);
  }
  {
    const int d = (NT - 1) & 1;
    const ushort_t* as = (d ? Ab1 : Ab0) + wm * 4096;
    const ushort_t* bsA = (d ? Bb1 : Bb0) + (wn * 2) * 4096;
    g256_iter<1>(as, bsA, bsA + 4096, nullptr, nullptr, nullptr, nullptr, rs,
                 slds, lr, lg, acc);
  }

  // epilogue
#pragma unroll
  for (int mi = 0; mi < 4; ++mi)
#pragma unroll
    for (int ci = 0; ci < 8; ++ci)
#pragma unroll
      for (int rr = 0; rr < 4; ++rr) {
        int m = m0 + wm * 64 + mi * 16 + lg * 4 + rr;
        int n = n0 + wn * 128 + ci * 16 + lr;
        size_t off = (size_t)m * N + n;
        float v = acc[mi][ci][rr];
        if constexpr (EPI == EPI_STORE) {
          CF[off] = v;
        } else if constexpr (EPI == EPI_STOREB) {
          CB[off] = f2bf(v);
        } else {
          float gv = bf2f(GINB[off]);
          float s = gv / (1.f + __expf(-gv));
          CB[off] = f2bf(s * v);
        }
      }
}

// ---------------------------------------------------------------------------
// Post-QKV: sum 2 split-K partials + per-head RMSNorm (q,k) + RoPE + bf16.
// ---------------------------------------------------------------------------
__global__ __launch_bounds__(256) void k_qkv_post(const float* __restrict__ Q0,
                                                  const float* __restrict__ Q1,
                                                  const float* __restrict__ QNW,
                                                  const float* __restrict__ KNW,
                                                  const int* __restrict__ POS,
                                                  ushort_t* __restrict__ Qb,
                                                  ushort_t* __restrict__ Kb,
                                                  ushort_t* __restrict__ Vb) {
  int t = blockIdx.x;
  int tid = threadIdx.x;
  int w = tid >> 6, l = tid & 63;
  float pos = (float)POS[t];
  const float* base0 = Q0 + (size_t)t * 4096;
  const float* base1 = Q1 + (size_t)t * 4096;
  int i0 = 2 * (l & 31);
  const float K2 = 19.931568569324174f / 64.f;  // log2(1e6)/64
  float ang0 = pos * exp2f(-(float)i0 * K2);
  float ang1 = pos * exp2f(-(float)(i0 + 1) * K2);
  float cs0 = cosf(ang0), sn0 = sinf(ang0);
  float cs1 = cosf(ang1), sn1 = sinf(ang1);
#pragma unroll
  for (int si = 0; si < 8; ++si) {
    int slot = w + si * 4;
    f32x2 xa = *(const f32x2*)(base0 + slot * 128 + l * 2);
    f32x2 xb = *(const f32x2*)(base1 + slot * 128 + l * 2);
    float v0 = xa.x + xb.x, v1 = xa.y + xb.y;
    float ss = v0 * v0 + v1 * v1;
#pragma unroll
    for (int o = 1; o < 64; o <<= 1) ss += __shfl_xor(ss, o, 64);
    if (slot < 24) {
      float sc = rsqrtf(ss / 128.f + 1e-6f);
      const float* wn = (slot < 16) ? QNW : KNW;
      f32x2 wv = *(const f32x2*)(wn + l * 2);
      v0 = v0 * sc * wv.x;
      v1 = v1 * sc * wv.y;
      float p0 = __shfl_xor(v0, 32, 64);
      float p1 = __shfl_xor(v1, 32, 64);
      float r0 = (l < 32) ? -p0 : p0;
      float r1 = (l < 32) ? -p1 : p1;
      v0 = v0 * cs0 + r0 * sn0;
      v1 = v1 * cs1 + r1 * sn1;
    }
    ushort2 uv;
    uv.x = f2bf(v0);
    uv.y = f2bf(v1);
    ushort_t* dst;
    if (slot < 16)
      dst = Qb + (size_t)t * 2048 + slot * 128 + l * 2;
    else if (slot < 24)
      dst = Kb + (size_t)t * 1024 + (slot - 16) * 128 + l * 2;
    else
      dst = Vb + (size_t)t * 1024 + (slot - 24) * 128 + l * 2;
    *(ushort2*)dst = uv;
  }
}

// ---------------------------------------------------------------------------
// Flash attention, ragged causal (segment) mask.  1 wave per (16 q rows, head).
// ---------------------------------------------------------------------------
__global__ __launch_bounds__(64) void k_flash(const ushort_t* __restrict__ Qb,
                                              const ushort_t* __restrict__ Kb,
                                              const ushort_t* __restrict__ VT,
                                              const int* __restrict__ SEG,
                                              ushort_t* __restrict__ Ob) {
  __shared__ ushort_t Pl[16 * 40];
  int l = threadIdx.x;
  int qt = blockIdx.x, h = blockIdx.y;
  int q0 = qt * 16;
  int lr = l & 15, lg = l >> 4;
  int kvh = h >> 1;
  bf16x8 qf[4];
  {
    const bf16x8* qv = (const bf16x8*)(Qb + (size_t)(q0 + lr) * 2048 + h * 128);
#pragma unroll
    for (int kk = 0; kk < 4; ++kk) qf[kk] = qv[kk * 4 + lg];
  }
  int segq[4];
#pragma unroll
  for (int r = 0; r < 4; ++r) segq[r] = SEG[q0 + lg * 4 + r];
  int target = SEG[q0];
  int lo = 0, hi = q0;
  while (lo < hi) {
    int mid = (lo + hi) >> 1;
    if (SEG[mid] < target) lo = mid + 1; else hi = mid;
  }
  int s_start = lo & ~31;
  float m_run[4], l_run[4];
  f32x4 acc[8] = {};
#pragma unroll
  for (int r = 0; r < 4; ++r) { m_run[r] = -1e30f; l_run[r] = 0.f; }
  const float scale = 0.08838834764831845f;  // 1/sqrt(128)
  for (int s0 = s_start; s0 < q0 + 16; s0 += 32) {
    int sa = s0 + lr, sb = s0 + 16 + lr;
    int sac = min(sa, T_SEQ - 1), sbc = min(sb, T_SEQ - 1);
    f32x4 SA = {}, SB = {};
    const bf16x8* ka = (const bf16x8*)(Kb + (size_t)sac * 1024 + kvh * 128);
    const bf16x8* kb = (const bf16x8*)(Kb + (size_t)sbc * 1024 + kvh * 128);
#pragma unroll
    for (int kk = 0; kk < 4; ++kk) {
      SA = __builtin_amdgcn_mfma_f32_16x16x32_bf16(qf[kk], ka[kk * 4 + lg], SA, 0, 0, 0);
      SB = __builtin_amdgcn_mfma_f32_16x16x32_bf16(qf[kk], kb[kk * 4 + lg], SB, 0, 0, 0);
    }
    int sga = SEG[sac], sgb = SEG[sbc];
    float al[4], pA[4], pB[4];
#pragma unroll
    for (int r = 0; r < 4; ++r) {
      int qrow = q0 + lg * 4 + r;
      float xa = (sa <= qrow && sga == segq[r]) ? SA[r] * scale : -1e30f;
      float xb = (sb <= qrow && sgb == segq[r]) ? SB[r] * scale : -1e30f;
      float mx = fmaxf(xa, xb);
#pragma unroll
      for (int o = 1; o < 16; o <<= 1) mx = fmaxf(mx, __shfl_xor(mx, o, 64));
      float nm = fmaxf(m_run[r], mx);
      float ea = __expf(xa - nm), eb = __expf(xb - nm);
      float rs = ea + eb;
#pragma unroll
      for (int o = 1; o < 16; o <<= 1) rs += __shfl_xor(rs, o, 64);
      al[r] = __expf(m_run[r] - nm);
      l_run[r] = l_run[r] * al[r] + rs;
      m_run[r] = nm;
      pA[r] = ea;
      pB[r] = eb;
    }
#pragma unroll
    for (int c = 0; c < 8; ++c)
#pragma unroll
      for (int r = 0; r < 4; ++r) acc[c][r] *= al[r];
    __syncthreads();
#pragma unroll
    for (int r = 0; r < 4; ++r) {
      Pl[(lg * 4 + r) * 40 + lr] = f2bf(pA[r]);
      Pl[(lg * 4 + r) * 40 + 16 + lr] = f2bf(pB[r]);
    }
    __syncthreads();
    bf16x8 pa = *(const bf16x8*)&Pl[lr * 40 + lg * 8];
    int sbase = min(s0 + lg * 8, T_SEQ - 8);
#pragma unroll
    for (int c = 0; c < 8; ++c) {
      bf16x8 vb = *(const bf16x8*)(VT + (size_t)(kvh * 128 + c * 16 + lr) * T_SEQ + sbase);
      acc[c] = __builtin_amdgcn_mfma_f32_16x16x32_bf16(pa, vb, acc[c], 0, 0, 0);
    }
  }
#pragma unroll
  for (int c = 0; c < 8; ++c)
#pragma unroll
    for (int r = 0; r < 4; ++r) {
      float ov = acc[c][r] / l_run[r];
      Ob[(size_t)(q0 + lg * 4 + r) * 2048 + h * 128 + c * 16 + lr] = f2bf(ov);
    }
}

// ---------------------------------------------------------------------------
extern "C" void kernel_launch(void* const* d_in, const int* in_sizes, int n_in,
                              void* d_out, int out_size, void* d_ws, size_t ws_size,
                              hipStream_t stream) {
  const float* hidden = (const float*)d_in[0];
  const float* ln1 = (const float*)d_in[1];
  const float* ln2 = (const float*)d_in[2];
  const float* wq = (const float*)d_in[3];
  const float* wk = (const float*)d_in[4];
  const float* wv = (const float*)d_in[5];
  const float* wo = (const float*)d_in[6];
  const float* qnw = (const float*)d_in[7];
  const float* knw = (const float*)d_in[8];
  const float* wg = (const float*)d_in[9];
  const float* wu = (const float*)d_in[10];
  const float* wd = (const float*)d_in[11];
  const float* fnw = (const float*)d_in[12];
  const int* seg = (const int*)d_in[13];
  const int* pos = (const int*)d_in[14];
  float* out = (float*)d_out;

  char* ws = (char*)d_ws;
  size_t off = 0;
  auto alloc = [&](size_t bytes) {
    char* p = ws + off;
    off += (bytes + 255) & ~(size_t)255;
    return p;
  };
  ushort_t* wT = (ushort_t*)alloc((size_t)DFF * DMODEL * 2);       // rotating
  ushort_t* hbuf = (ushort_t*)alloc((size_t)T_SEQ * DMODEL * 2);
  ushort_t* qb = (ushort_t*)alloc((size_t)T_SEQ * 2048 * 2);
  ushort_t* kb = (ushort_t*)alloc((size_t)T_SEQ * 1024 * 2);
  ushort_t* vb = (ushort_t*)alloc((size_t)T_SEQ * 1024 * 2);
  ushort_t* vT = (ushort_t*)alloc((size_t)T_SEQ * 1024 * 2);
  ushort_t* ob = (ushort_t*)alloc((size_t)T_SEQ * 2048 * 2);
  float* gbufF = (float*)alloc((size_t)T_SEQ * DFF * 4);           // 67MB scratch
  ushort_t* gbufB = (ushort_t*)gbufF;                              // bf16 view
  ushort_t* mbuf = (ushort_t*)alloc((size_t)T_SEQ * DFF * 2);
  (void)ws_size; (void)in_sizes; (void)n_in; (void)out_size;

  dim3 b256(256), b64(64), b512(512);
  for (int lyr = 0; lyr < 2; ++lyr) {
    const float* xsrc = (lyr == 0) ? hidden : out;
    k_rmsnorm<1><<<T_SEQ, b256, 0, stream>>>(xsrc, ln1 + (size_t)lyr * DMODEL, hbuf);

    const float* wql = wq + (size_t)lyr * DMODEL * 2048;
    const float* wkl = wk + (size_t)lyr * DMODEL * 1024;
    const float* wvl = wv + (size_t)lyr * DMODEL * 1024;
    k_transpose_bf16<float><<<dim3(32, 32), b256, 0, stream>>>(wql, wT, 2048, 2048);
    k_transpose_bf16<float><<<dim3(16, 32), b256, 0, stream>>>(wkl, wT + (size_t)2048 * 2048, 2048, 1024);
    k_transpose_bf16<float><<<dim3(16, 32), b256, 0, stream>>>(wvl, wT + (size_t)3072 * 2048, 2048, 1024);
    // QKV split-K=2 (Kc=1024): partials -> gbufF[z * 2048*4096]
    k_gemm256<EPI_STORE><<<dim3(16, 8, 2), b512, 0, stream>>>(
        hbuf, wT, nullptr, gbufF, nullptr, 4096, 2048, 1024, (size_t)2048 * 4096);
    k_qkv_post<<<T_SEQ, b256, 0, stream>>>(gbufF, gbufF + (size_t)2048 * 4096,
                                           qnw + (size_t)lyr * 128, knw + (size_t)lyr * 128,
                                           pos, qb, kb, vb);
    k_transpose_bf16<ushort_t><<<dim3(16, 32), b256, 0, stream>>>(vb, vT, 2048, 1024);
    k_flash<<<dim3(T_SEQ / 16, NH), b64, 0, stream>>>(qb, kb, vT, seg, ob);

    const float* wol = wo + (size_t)lyr * 2048 * DMODEL;
    k_transpose_bf16<float><<<dim3(32, 32), b256, 0, stream>>>(wol, wT, 2048, 2048);
    // WO split-K=4 (Kc=512): partials -> gbufF[z * 2048*2048], then +residual
    k_gemm256<EPI_STORE><<<dim3(8, 8, 4), b512, 0, stream>>>(
        ob, wT, nullptr, gbufF, nullptr, 2048, 2048, 512, (size_t)2048 * 2048);
    k_red4res<<<4096, b256, 0, stream>>>(gbufF, xsrc, out, 2048 * 2048);

    k_rmsnorm<1><<<T_SEQ, b256, 0, stream>>>(out, ln2 + (size_t)lyr * DMODEL, hbuf);

    const float* wgl = wg + (size_t)lyr * DMODEL * DFF;
    const float* wul = wu + (size_t)lyr * DMODEL * DFF;
    const float* wdl = wd + (size_t)lyr * DFF * DMODEL;
    k_transpose_bf16<float><<<dim3(128, 32), b256, 0, stream>>>(wgl, wT, 2048, 8192);
    k_gemm256<EPI_STOREB><<<dim3(32, 8, 1), b512, 0, stream>>>(
        hbuf, wT, nullptr, nullptr, gbufB, 8192, 2048, 2048, 0);
    k_transpose_bf16<float><<<dim3(128, 32), b256, 0, stream>>>(wul, wT, 2048, 8192);
    k_gemm256<EPI_SILU><<<dim3(32, 8, 1), b512, 0, stream>>>(
        hbuf, wT, gbufB, nullptr, mbuf, 8192, 2048, 2048, 0);
    k_transpose_bf16<float><<<dim3(32, 128), b256, 0, stream>>>(wdl, wT, 8192, 2048);
    // WD split-K=4 (Kc=2048): partials -> gbufF[z * 2048*2048], then +residual
    k_gemm256<EPI_STORE><<<dim3(8, 8, 4), b512, 0, stream>>>(
        mbuf, wT, nullptr, gbufF, nullptr, 2048, 8192, 2048, (size_t)2048 * 2048);
    k_red4res<<<4096, b256, 0, stream>>>(gbufF, out, out, 2048 * 2048);
  }
  k_rmsnorm<0><<<T_SEQ, b256, 0, stream>>>(out, fnw, out);
}